// Round 2
// baseline (1674.023 us; speedup 1.0000x reference)
//
#include <hip/hip_runtime.h>

// ---------------------------------------------------------------------------
// TPAttention (T5-style rel-bias attention + TPR role binding), fp32 baseline.
// Stages:
//  1) build_bias_tab: bias_tab[rel+1023][h] = rel_bias[bucket(rel)][h]
//  2) normalize_R:    RM[r][d] = R[r][d] / ||R[r]||
//  3) gemm (x3, scatter epilogue): q,k,v = input @ W{q,k,v} -> [b,h,s,d]
//  4) attn_f32: flash attention with bias, writes v_bar in unshaped layout
//  5) gemm (+bias): role_scores = v_bar_unshaped @ Wr + br
//  6) role_bind: softmax over 64 roles, roles = attn @ RM, bound = v_bar*roles
//  7) gemm: out = bound_unshaped @ Wo
// ---------------------------------------------------------------------------

#define N_HEADS 16
#define D_KV 64
#define QLEN 1024
#define BS 4
#define DMODEL 1024
#define NROWS (BS * QLEN)          // 4096

// ============================ bias table ====================================
__global__ void build_bias_tab(const float* __restrict__ rel_bias,
                               float* __restrict__ tab) {
  int idx = blockIdx.x * 256 + threadIdx.x;   // [0, 2047*16)
  if (idx >= 2047 * 16) return;
  int rel = idx / 16 - 1023;                  // rel = k - q
  int h   = idx % 16;
  int n = -rel;                               // q - k
  int ret = 0;
  if (n < 0) { ret = 16; n = -n; }
  int b;
  if (n < 8) {
    b = n;
  } else {
    // floor(2*log2(n)) exactly via integer math; val = 8 + floor(2*log2(n/8))
    int e  = 31 - __builtin_clz((unsigned)n);
    int f2 = 2 * e + ((n * n >= (1 << (2 * e + 1))) ? 1 : 0);
    int val = f2 - 6 + 8;
    b = val > 15 ? 15 : val;
  }
  b += ret;
  tab[idx] = rel_bias[b * 16 + h];
}

// ============================ R normalization ===============================
__global__ void normalize_R(const float* __restrict__ R, float* __restrict__ RM) {
  int r = blockIdx.x;        // 64
  int d = threadIdx.x;       // 64 (one wave)
  float v = R[r * 64 + d];
  float ss = v * v;
  #pragma unroll
  for (int o = 32; o; o >>= 1) ss += __shfl_xor(ss, o);
  RM[r * 64 + d] = v / sqrtf(ss);
}

// ============================ fp32 SGEMM ====================================
// C[M,N] = A[M,K] @ B[K,N] (+bias). mode 0: row-major C. mode 1: scatter to
// [b,h,s,d]: b=row>>10, s=row&1023, h=col>>6, d=col&63.
#define BM 128
#define BN 128
#define BKG 16
#define BMP 132   // padded leading dim for As (2-way-free staging stores)
__global__ __launch_bounds__(256) void gemm_f32(
    const float* __restrict__ A, const float* __restrict__ B,
    const float* __restrict__ bias, float* __restrict__ C,
    int M, int N, int K, int mode) {
  __shared__ float As[BKG][BMP];  // transposed A tile (row stride 528B, 16B-aligned)
  __shared__ float Bs[BKG][BN];
  int tid = threadIdx.x;
  int row0 = blockIdx.y * BM, col0 = blockIdx.x * BN;
  int tx = tid & 15, ty = tid >> 4;
  float acc[8][8] = {};

  for (int k0 = 0; k0 < K; k0 += BKG) {
    #pragma unroll
    for (int p = 0; p < 2; ++p) {
      int idx = tid + p * 256;             // 0..511
      int r = idx >> 2, c4 = (idx & 3) << 2;
      float4 v = *(const float4*)(A + (size_t)(row0 + r) * K + k0 + c4);
      As[c4 + 0][r] = v.x; As[c4 + 1][r] = v.y;
      As[c4 + 2][r] = v.z; As[c4 + 3][r] = v.w;
    }
    #pragma unroll
    for (int p = 0; p < 2; ++p) {
      int idx = tid + p * 256;
      int r = idx >> 5, c4 = (idx & 31) << 2;
      *(float4*)(&Bs[r][c4]) = *(const float4*)(B + (size_t)(k0 + r) * N + col0 + c4);
    }
    __syncthreads();
    #pragma unroll
    for (int kk = 0; kk < BKG; ++kk) {
      float a[8], b[8];
      *(float4*)(a)     = *(float4*)(&As[kk][ty * 4]);
      *(float4*)(a + 4) = *(float4*)(&As[kk][64 + ty * 4]);
      *(float4*)(b)     = *(float4*)(&Bs[kk][tx * 4]);
      *(float4*)(b + 4) = *(float4*)(&Bs[kk][64 + tx * 4]);
      #pragma unroll
      for (int i = 0; i < 8; ++i)
        #pragma unroll
        for (int j = 0; j < 8; ++j)
          acc[i][j] += a[i] * b[j];
    }
    __syncthreads();
  }

  #pragma unroll
  for (int i = 0; i < 8; ++i) {
    int r = row0 + ((i < 4) ? (ty * 4 + i) : (64 + ty * 4 + (i - 4)));
    #pragma unroll
    for (int jj = 0; jj < 2; ++jj) {
      int c = col0 + ((jj == 0) ? (tx * 4) : (64 + tx * 4));
      float4 v = make_float4(acc[i][jj * 4 + 0], acc[i][jj * 4 + 1],
                             acc[i][jj * 4 + 2], acc[i][jj * 4 + 3]);
      if (bias) {
        v.x += bias[c]; v.y += bias[c + 1]; v.z += bias[c + 2]; v.w += bias[c + 3];
      }
      if (mode == 0) {
        *(float4*)(C + (size_t)r * N + c) = v;
      } else {
        int b_ = r >> 10, s = r & 1023, h = c >> 6, d = c & 63;
        *(float4*)(C + ((size_t)(b_ * 16 + h) << 16) + (s << 6) + d) = v;
      }
    }
  }
}

// ============================ flash attention ===============================
// grid: (QLEN/BQ, BS*N_HEADS). block 256. Q,K,V in [b,h,s,d].
// Writes v_bar in UNSHAPED layout: vbar[(b*1024+q)*1024 + h*64 + d].
#define BQ 32
#define BKV 64
__global__ __launch_bounds__(256) void attn_f32(
    const float* __restrict__ Q, const float* __restrict__ K,
    const float* __restrict__ V, const float* __restrict__ bias_tab,
    float* __restrict__ Vbar) {
  __shared__ float Qs[BQ][68];
  __shared__ float Ks[BKV][68];
  __shared__ float Vs[BKV][64];
  __shared__ float Ss[BQ][65];

  int tid = threadIdx.x;
  int bh = blockIdx.y;                 // 0..63
  int h = bh & 15;
  int q0 = blockIdx.x * BQ;
  const float* Qb = Q + (size_t)bh * QLEN * 64;
  const float* Kb = K + (size_t)bh * QLEN * 64;
  const float* Vb = V + (size_t)bh * QLEN * 64;

  // stage Q tile (32x64)
  #pragma unroll
  for (int p = 0; p < 2; ++p) {
    int idx = tid + p * 256;
    int r = idx >> 4, c4 = (idx & 15) << 2;
    *(float4*)(&Qs[r][c4]) = *(const float4*)(Qb + (size_t)(q0 + r) * 64 + c4);
  }
  __syncthreads();

  int si = tid >> 3;      // S row (0..31)
  int sj = tid & 7;       // col group (0..7)

  // own Q row into registers (reused every k-tile)
  float qreg[64];
  #pragma unroll
  for (int kk = 0; kk < 64; kk += 4) {
    float4 qv = *(float4*)(&Qs[si][kk]);
    qreg[kk] = qv.x; qreg[kk + 1] = qv.y; qreg[kk + 2] = qv.z; qreg[kk + 3] = qv.w;
  }

  float m_run = -1e30f, l_run = 0.f;
  float o[8] = {};

  for (int k0 = 0; k0 < QLEN; k0 += BKV) {
    #pragma unroll
    for (int p = 0; p < 4; ++p) {
      int idx = tid + p * 256;
      int r = idx >> 4, c4 = (idx & 15) << 2;
      *(float4*)(&Ks[r][c4]) = *(const float4*)(Kb + (size_t)(k0 + r) * 64 + c4);
      *(float4*)(&Vs[r][c4]) = *(const float4*)(Vb + (size_t)(k0 + r) * 64 + c4);
    }
    __syncthreads();

    // scores for 8 columns j = sj + 8m
    float sv[8];
    #pragma unroll
    for (int mm = 0; mm < 8; ++mm) {
      int j = sj + (mm << 3);
      float acc = 0.f;
      #pragma unroll
      for (int kk = 0; kk < 64; kk += 4) {
        float4 kv = *(float4*)(&Ks[j][kk]);
        acc += qreg[kk] * kv.x + qreg[kk + 1] * kv.y +
               qreg[kk + 2] * kv.z + qreg[kk + 3] * kv.w;
      }
      acc += bias_tab[(size_t)((k0 + j) - (q0 + si) + 1023) * 16 + h];
      sv[mm] = acc;
    }

    // online softmax over this tile's row chunk (8 lanes per row)
    float mx = sv[0];
    #pragma unroll
    for (int mm = 1; mm < 8; ++mm) mx = fmaxf(mx, sv[mm]);
    #pragma unroll
    for (int o_ = 1; o_ < 8; o_ <<= 1) mx = fmaxf(mx, __shfl_xor(mx, o_));
    float m_new = fmaxf(m_run, mx);
    float p_sum = 0.f;
    #pragma unroll
    for (int mm = 0; mm < 8; ++mm) { sv[mm] = expf(sv[mm] - m_new); p_sum += sv[mm]; }
    #pragma unroll
    for (int o_ = 1; o_ < 8; o_ <<= 1) p_sum += __shfl_xor(p_sum, o_);
    float scale = expf(m_run - m_new);
    l_run = l_run * scale + p_sum;
    m_run = m_new;

    #pragma unroll
    for (int mm = 0; mm < 8; ++mm) Ss[si][sj + (mm << 3)] = sv[mm];
    __syncthreads();   // make P visible (no reliance on wave-sync LDS order)

    #pragma unroll
    for (int c = 0; c < 8; ++c) o[c] *= scale;
    #pragma unroll
    for (int j = 0; j < 64; ++j) {
      float p = Ss[si][j];
      #pragma unroll
      for (int c = 0; c < 8; ++c) o[c] += p * Vs[j][sj * 8 + c];
    }
    __syncthreads();   // protect Ks/Vs/Ss before next staging
  }

  float inv = 1.f / l_run;
  #pragma unroll
  for (int c = 0; c < 8; ++c) o[c] *= inv;
  // unshaped write: [(b*1024 + q)*1024 + h*64 + d]
  int b_ = bh >> 4;
  float* dst = Vbar + ((size_t)(b_ * QLEN + q0 + si) << 10) + h * 64 + sj * 8;
  *(float4*)(dst)     = make_float4(o[0], o[1], o[2], o[3]);
  *(float4*)(dst + 4) = make_float4(o[4], o[5], o[6], o[7]);
}

// ============================ role binding ==================================
// role_scores: [4096][1024] (= [b*1024+q][h*64+r]); v_bar unshaped; writes
// bound unshaped [4096][1024].
__global__ __launch_bounds__(256) void role_bind(
    const float* __restrict__ role_scores, const float* __restrict__ RM,
    const float* __restrict__ v_bar, float* __restrict__ bound) {
  __shared__ float rm[64][64];
  int tid = threadIdx.x;
  #pragma unroll
  for (int p = 0; p < 4; ++p) {
    int idx = tid + p * 256;
    ((float4*)rm)[idx] = ((const float4*)RM)[idx];
  }
  __syncthreads();
  int wave = tid >> 6, lane = tid & 63;
  #pragma unroll
  for (int i = 0; i < 4; ++i) {
    int row = blockIdx.x * 16 + wave * 4 + i;   // [0, 65536)
    int bq = row >> 4, h = row & 15;
    float s = role_scores[((size_t)bq << 10) + h * 64 + lane];
    float m = s;
    #pragma unroll
    for (int o = 32; o; o >>= 1) m = fmaxf(m, __shfl_xor(m, o));
    float e = expf(s - m);
    float l = e;
    #pragma unroll
    for (int o = 32; o; o >>= 1) l += __shfl_xor(l, o);
    float a = e / l;
    float rd = 0.f;
    #pragma unroll
    for (int r = 0; r < 64; ++r) rd += __shfl(a, r) * rm[r][lane];
    size_t idx = ((size_t)bq << 10) + h * 64 + lane;
    bound[idx] = v_bar[idx] * rd;
  }
}

// ============================ launcher ======================================
extern "C" void kernel_launch(void* const* d_in, const int* in_sizes, int n_in,
                              void* d_out, int out_size, void* d_ws, size_t ws_size,
                              hipStream_t stream) {
  const float* input    = (const float*)d_in[0];
  const float* Wq       = (const float*)d_in[1];
  const float* Wk       = (const float*)d_in[2];
  const float* Wv       = (const float*)d_in[3];
  const float* Wo       = (const float*)d_in[4];
  const float* Wr       = (const float*)d_in[5];
  const float* br       = (const float*)d_in[6];
  const float* R        = (const float*)d_in[7];
  const float* rel_bias = (const float*)d_in[8];
  float* out = (float*)d_out;

  float* ws = (float*)d_ws;
  const size_t SEG = (size_t)BS * N_HEADS * QLEN * D_KV;  // 4M floats
  float* q_ws    = ws;                  // later reused as role_scores
  float* k_ws    = ws + SEG;            // later reused as bound
  float* v_ws    = ws + 2 * SEG;
  float* vbar_ws = ws + 3 * SEG;        // unshaped [4096][1024]
  float* rm_ws   = ws + 4 * SEG;        // 4096 floats
  float* tab_ws  = rm_ws + 4096;        // 2047*16 floats
  float* rs_ws   = q_ws;                // role_scores [4096][1024]
  float* bound_ws= k_ws;                // bound unshaped [4096][1024]

  // 1) bias table, 2) normalized roles
  build_bias_tab<<<dim3((2047 * 16 + 255) / 256), dim3(256), 0, stream>>>(rel_bias, tab_ws);
  normalize_R<<<dim3(64), dim3(64), 0, stream>>>(R, rm_ws);

  // 3) q,k,v projections (scatter to [b,h,s,d])
  dim3 gg(DMODEL / BN, NROWS / BM);   // (8, 32)
  gemm_f32<<<gg, 256, 0, stream>>>(input, Wq, nullptr, q_ws, NROWS, DMODEL, DMODEL, 1);
  gemm_f32<<<gg, 256, 0, stream>>>(input, Wk, nullptr, k_ws, NROWS, DMODEL, DMODEL, 1);
  gemm_f32<<<gg, 256, 0, stream>>>(input, Wv, nullptr, v_ws, NROWS, DMODEL, DMODEL, 1);

  // 4) fused attention (reads q_ws/k_ws; they are only reused AFTER this kernel)
  attn_f32<<<dim3(QLEN / BQ, BS * N_HEADS), 256, 0, stream>>>(q_ws, k_ws, v_ws, tab_ws, vbar_ws);

  // 5) role scores = vbar_unshaped @ Wr + br
  gemm_f32<<<gg, 256, 0, stream>>>(vbar_ws, Wr, br, rs_ws, NROWS, DMODEL, DMODEL, 0);

  // 6) role softmax + binding
  role_bind<<<dim3(4096), 256, 0, stream>>>(rs_ws, rm_ws, vbar_ws, bound_ws);

  // 7) output projection
  gemm_f32<<<gg, 256, 0, stream>>>(bound_ws, Wo, nullptr, out, NROWS, DMODEL, DMODEL, 0);
}

// Round 5
// 1077.902 us; speedup vs baseline: 1.5530x; 1.5530x over previous
//
#include <hip/hip_runtime.h>

// ---------------------------------------------------------------------------
// TPAttention: fp16x3-split MFMA GEMMs + fp32 flash attention.
//  1) build_bias_tab, normalize_R, split_rows(input -> hi/lo fp16 in d_out)
//  2) transpose_split(W) -> WT hi/lo [N][K];  gemm16 (MFMA f16, 3-term split)
//  3) attn_f32 (unchanged math), writes v_bar as hi/lo fp16 (unshaped)
//  4) gemm16 role_scores (+bias), role_bind -> bound hi/lo, gemm16 -> out
// Workspace aliasing keeps total at 64.2 MB (proven safe in round 2).
// ---------------------------------------------------------------------------

typedef _Float16 f16;
typedef _Float16 f16x8 __attribute__((ext_vector_type(8)));
typedef float f32x4 __attribute__((ext_vector_type(4)));

#define N_HEADS 16
#define D_KV 64
#define QLEN 1024
#define BS 4
#define DMODEL 1024
#define NROWS (BS * QLEN)   // 4096
#define KDIM 1024

// async global->LDS, 16B per lane; LDS dest = uniform base + lane*16
__device__ __forceinline__ void ldsload16(const void* g, void* l) {
  __builtin_amdgcn_global_load_lds(
      (const __attribute__((address_space(1))) void*)g,
      (__attribute__((address_space(3))) void*)l, 16, 0, 0);
}

// ============================ bias table ====================================
__global__ void build_bias_tab(const float* __restrict__ rel_bias,
                               float* __restrict__ tab) {
  int idx = blockIdx.x * 256 + threadIdx.x;   // [0, 2047*16)
  if (idx >= 2047 * 16) return;
  int rel = idx / 16 - 1023;                  // rel = k - q
  int h   = idx % 16;
  int n = -rel;                               // q - k
  int ret = 0;
  if (n < 0) { ret = 16; n = -n; }
  int b;
  if (n < 8) {
    b = n;
  } else {
    int e  = 31 - __builtin_clz((unsigned)n);
    int f2 = 2 * e + ((n * n >= (1 << (2 * e + 1))) ? 1 : 0);
    int val = f2 - 6 + 8;
    b = val > 15 ? 15 : val;
  }
  b += ret;
  tab[idx] = rel_bias[b * 16 + h];
}

// ============================ R normalization ===============================
__global__ void normalize_R(const float* __restrict__ R, float* __restrict__ RM) {
  int r = blockIdx.x;        // 64
  int d = threadIdx.x;       // 64 (one wave)
  float v = R[r * 64 + d];
  float ss = v * v;
  #pragma unroll
  for (int o = 32; o; o >>= 1) ss += __shfl_xor(ss, o);
  RM[r * 64 + d] = v / sqrtf(ss);
}

// ============================ fp32 -> hi/lo fp16 split ======================
__global__ __launch_bounds__(256) void split_rows(
    const float* __restrict__ X, f16* __restrict__ Hi, f16* __restrict__ Lo) {
  size_t i = ((size_t)blockIdx.x * 256 + threadIdx.x) * 8;
  float4 v0 = *(const float4*)(X + i);
  float4 v1 = *(const float4*)(X + i + 4);
  float xs[8] = {v0.x, v0.y, v0.z, v0.w, v1.x, v1.y, v1.z, v1.w};
  f16x8 h8, l8;
  #pragma unroll
  for (int j = 0; j < 8; ++j) {
    f16 h = (f16)xs[j];
    h8[j] = h;
    l8[j] = (f16)(xs[j] - (float)h);
  }
  *(f16x8*)(Hi + i) = h8;
  *(f16x8*)(Lo + i) = l8;
}

// ============== W[K][N] f32 -> WT hi/lo fp16 [N][K] (64x64 tiles) ===========
__global__ __launch_bounds__(256) void transpose_split(
    const float* __restrict__ W, f16* __restrict__ Thi, f16* __restrict__ Tlo) {
  __shared__ float tile[64][65];
  int tid = threadIdx.x;
  int n0 = (blockIdx.x & 15) * 64, k0 = (blockIdx.x >> 4) * 64;
  #pragma unroll
  for (int it = 0; it < 16; ++it) {
    int idx = it * 256 + tid;
    int r = idx >> 6, c = idx & 63;
    tile[r][c] = W[(size_t)(k0 + r) * DMODEL + n0 + c];
  }
  __syncthreads();
  #pragma unroll
  for (int it = 0; it < 16; ++it) {
    int idx = it * 256 + tid;
    int rr = idx >> 6, cc = idx & 63;
    float x = tile[cc][rr];
    f16 hv = (f16)x;
    size_t o = (size_t)(n0 + rr) * KDIM + k0 + cc;
    Thi[o] = hv;
    Tlo[o] = (f16)(x - (float)hv);
  }
}

// ============================ fp16x3 MFMA GEMM ==============================
// C[4096][1024] = (Ahi+Alo)[M][K] @ (Bhi+Blo)^T where B given as [N][K].
// Tile 128x64, BK=32, 4 waves (2x2), wave-tile 64x32, frags 4x2.
// LDS is fragment-major: each 16-row group's wave-fragment stored as
// lane-contiguous 1KB => conflict-free ds_read_b128; staged by
// global_load_lds with per-lane global addresses.
// EPI: 0 = plain f32 [M][1024]; 1 = scatter to [b,h,s,d]; 2 = +bias f32.
#define GBM 128
#define GBN 64
#define GBK 32
template<int EPI>
__global__ __launch_bounds__(256) void gemm16(
    const f16* __restrict__ Ahi, const f16* __restrict__ Alo,
    const f16* __restrict__ Bhi, const f16* __restrict__ Blo,
    const float* __restrict__ bias, float* __restrict__ C) {
  __shared__ __align__(16) char smem[24 * 1024];
  char* AHI = smem;              // 8 groups * 1KB
  char* ALO = smem + 8192;
  char* BHI = smem + 16384;      // 4 groups * 1KB
  char* BLO = smem + 20480;

  const int tid = threadIdx.x;
  const int lane = tid & 63, wid = tid >> 6;
  const int wr = wid >> 1, wc = wid & 1;
  const int row0 = blockIdx.y * GBM, col0 = blockIdx.x * GBN;
  const int lr = lane & 15, lk = (lane >> 4) << 3;   // frag row, frag k-offset

  // per-lane global offsets (f16 element units)
  const size_t aoff0 = (size_t)(row0 + wid * 16 + lr) * KDIM + lk;
  const size_t aoff1 = (size_t)(row0 + (wid + 4) * 16 + lr) * KDIM + lk;
  const size_t boff  = (size_t)(col0 + wid * 16 + lr) * KDIM + lk;

  f32x4 acc[4][2] = {};

  for (int k0 = 0; k0 < KDIM; k0 += GBK) {
    // stage: each wave fills A-groups {wid, wid+4} (hi & lo) and B-group wid
    ldsload16(Ahi + aoff0 + k0, AHI + wid * 1024);
    ldsload16(Ahi + aoff1 + k0, AHI + (wid + 4) * 1024);
    ldsload16(Alo + aoff0 + k0, ALO + wid * 1024);
    ldsload16(Alo + aoff1 + k0, ALO + (wid + 4) * 1024);
    ldsload16(Bhi + boff + k0, BHI + wid * 1024);
    ldsload16(Blo + boff + k0, BLO + wid * 1024);
    __syncthreads();   // drains vmcnt (global_load_lds) + barrier

    f16x8 ah[4], al[4], bh[2], bl[2];
    #pragma unroll
    for (int mi = 0; mi < 4; ++mi) {
      ah[mi] = *(const f16x8*)(AHI + (wr * 4 + mi) * 1024 + lane * 16);
      al[mi] = *(const f16x8*)(ALO + (wr * 4 + mi) * 1024 + lane * 16);
    }
    #pragma unroll
    for (int ni = 0; ni < 2; ++ni) {
      bh[ni] = *(const f16x8*)(BHI + (wc * 2 + ni) * 1024 + lane * 16);
      bl[ni] = *(const f16x8*)(BLO + (wc * 2 + ni) * 1024 + lane * 16);
    }
    #pragma unroll
    for (int mi = 0; mi < 4; ++mi)
      #pragma unroll
      for (int ni = 0; ni < 2; ++ni) {
        acc[mi][ni] = __builtin_amdgcn_mfma_f32_16x16x32_f16(ah[mi], bh[ni], acc[mi][ni], 0, 0, 0);
        acc[mi][ni] = __builtin_amdgcn_mfma_f32_16x16x32_f16(al[mi], bh[ni], acc[mi][ni], 0, 0, 0);
        acc[mi][ni] = __builtin_amdgcn_mfma_f32_16x16x32_f16(ah[mi], bl[ni], acc[mi][ni], 0, 0, 0);
      }
    __syncthreads();   // all reads done before next stage overwrites
  }

  // epilogue: C/D frag mapping col = lane&15, row = (lane>>4)*4 + reg
  #pragma unroll
  for (int mi = 0; mi < 4; ++mi) {
    #pragma unroll
    for (int ni = 0; ni < 2; ++ni) {
      int c = col0 + wc * 32 + ni * 16 + lr;
      #pragma unroll
      for (int r = 0; r < 4; ++r) {
        int rr = row0 + wr * 64 + mi * 16 + (lane >> 4) * 4 + r;
        float v = acc[mi][ni][r];
        if (EPI == 2) v += bias[c];
        if (EPI == 1) {
          int b_ = rr >> 10, s = rr & 1023, h = c >> 6, d = c & 63;
          C[((size_t)(b_ * 16 + h) << 16) + (s << 6) + d] = v;
        } else {
          C[(size_t)rr * DMODEL + c] = v;
        }
      }
    }
  }
}

// ============================ flash attention ===============================
// grid: (QLEN/BQ, BS*N_HEADS). block 256. Q,K,V fp32 in [b,h,s,d].
// Writes v_bar as hi/lo fp16 in UNSHAPED layout [(b*1024+q)*1024 + h*64 + d].
#define BQ 32
#define BKV 64
__global__ __launch_bounds__(256) void attn_f32(
    const float* __restrict__ Q, const float* __restrict__ K,
    const float* __restrict__ V, const float* __restrict__ bias_tab,
    f16* __restrict__ Vhi, f16* __restrict__ Vlo) {
  __shared__ float Qs[BQ][68];
  __shared__ float Ks[BKV][68];
  __shared__ float Vs[BKV][64];
  __shared__ float Ss[BQ][65];

  int tid = threadIdx.x;
  int bh = blockIdx.y;                 // 0..63
  int h = bh & 15;
  int q0 = blockIdx.x * BQ;
  const float* Qb = Q + (size_t)bh * QLEN * 64;
  const float* Kb = K + (size_t)bh * QLEN * 64;
  const float* Vb = V + (size_t)bh * QLEN * 64;

  #pragma unroll
  for (int p = 0; p < 2; ++p) {
    int idx = tid + p * 256;
    int r = idx >> 4, c4 = (idx & 15) << 2;
    *(float4*)(&Qs[r][c4]) = *(const float4*)(Qb + (size_t)(q0 + r) * 64 + c4);
  }
  __syncthreads();

  int si = tid >> 3;      // S row (0..31)
  int sj = tid & 7;       // col group (0..7)

  float qreg[64];
  #pragma unroll
  for (int kk = 0; kk < 64; kk += 4) {
    float4 qv = *(float4*)(&Qs[si][kk]);
    qreg[kk] = qv.x; qreg[kk + 1] = qv.y; qreg[kk + 2] = qv.z; qreg[kk + 3] = qv.w;
  }

  float m_run = -1e30f, l_run = 0.f;
  float o[8] = {};

  for (int k0 = 0; k0 < QLEN; k0 += BKV) {
    #pragma unroll
    for (int p = 0; p < 4; ++p) {
      int idx = tid + p * 256;
      int r = idx >> 4, c4 = (idx & 15) << 2;
      *(float4*)(&Ks[r][c4]) = *(const float4*)(Kb + (size_t)(k0 + r) * 64 + c4);
      *(float4*)(&Vs[r][c4]) = *(const float4*)(Vb + (size_t)(k0 + r) * 64 + c4);
    }
    __syncthreads();

    float sv[8];
    #pragma unroll
    for (int mm = 0; mm < 8; ++mm) {
      int j = sj + (mm << 3);
      float acc = 0.f;
      #pragma unroll
      for (int kk = 0; kk < 64; kk += 4) {
        float4 kv = *(float4*)(&Ks[j][kk]);
        acc += qreg[kk] * kv.x + qreg[kk + 1] * kv.y +
               qreg[kk + 2] * kv.z + qreg[kk + 3] * kv.w;
      }
      acc += bias_tab[(size_t)((k0 + j) - (q0 + si) + 1023) * 16 + h];
      sv[mm] = acc;
    }

    float mx = sv[0];
    #pragma unroll
    for (int mm = 1; mm < 8; ++mm) mx = fmaxf(mx, sv[mm]);
    #pragma unroll
    for (int o_ = 1; o_ < 8; o_ <<= 1) mx = fmaxf(mx, __shfl_xor(mx, o_));
    float m_new = fmaxf(m_run, mx);
    float p_sum = 0.f;
    #pragma unroll
    for (int mm = 0; mm < 8; ++mm) { sv[mm] = expf(sv[mm] - m_new); p_sum += sv[mm]; }
    #pragma unroll
    for (int o_ = 1; o_ < 8; o_ <<= 1) p_sum += __shfl_xor(p_sum, o_);
    float scale = expf(m_run - m_new);
    l_run = l_run * scale + p_sum;
    m_run = m_new;

    #pragma unroll
    for (int mm = 0; mm < 8; ++mm) Ss[si][sj + (mm << 3)] = sv[mm];
    __syncthreads();

    #pragma unroll
    for (int c = 0; c < 8; ++c) o[c] *= scale;
    #pragma unroll
    for (int j = 0; j < 64; ++j) {
      float p = Ss[si][j];
      #pragma unroll
      for (int c = 0; c < 8; ++c) o[c] += p * Vs[j][sj * 8 + c];
    }
    __syncthreads();
  }

  float inv = 1.f / l_run;
  f16x8 h8, l8;
  #pragma unroll
  for (int c = 0; c < 8; ++c) {
    float x = o[c] * inv;
    f16 hv = (f16)x;
    h8[c] = hv;
    l8[c] = (f16)(x - (float)hv);
  }
  int b_ = bh >> 4;
  size_t base = ((size_t)(b_ * QLEN + q0 + si) << 10) + h * 64 + sj * 8;
  *(f16x8*)(Vhi + base) = h8;
  *(f16x8*)(Vlo + base) = l8;
}

// ============================ role binding ==================================
// role_scores f32 [4096][1024]; vbar hi/lo fp16 unshaped; writes bound hi/lo.
__global__ __launch_bounds__(256) void role_bind(
    const float* __restrict__ role_scores, const float* __restrict__ RM,
    const f16* __restrict__ Vhi, const f16* __restrict__ Vlo,
    f16* __restrict__ Bhi, f16* __restrict__ Blo) {
  __shared__ float rm[64][64];
  int tid = threadIdx.x;
  #pragma unroll
  for (int p = 0; p < 4; ++p) {
    int idx = tid + p * 256;
    ((float4*)rm)[idx] = ((const float4*)RM)[idx];
  }
  __syncthreads();
  int wave = tid >> 6, lane = tid & 63;
  #pragma unroll
  for (int i = 0; i < 4; ++i) {
    int row = blockIdx.x * 16 + wave * 4 + i;   // [0, 65536)
    int bq = row >> 4, h = row & 15;
    float s = role_scores[((size_t)bq << 10) + h * 64 + lane];
    float m = s;
    #pragma unroll
    for (int o = 32; o; o >>= 1) m = fmaxf(m, __shfl_xor(m, o));
    float e = expf(s - m);
    float l = e;
    #pragma unroll
    for (int o = 32; o; o >>= 1) l += __shfl_xor(l, o);
    float a = e / l;
    float rd = 0.f;
    #pragma unroll
    for (int r = 0; r < 64; ++r) rd += __shfl(a, r) * rm[r][lane];
    size_t idx = ((size_t)bq << 10) + h * 64 + lane;
    float vb = (float)Vhi[idx] + (float)Vlo[idx];
    float x = vb * rd;
    f16 hv = (f16)x;
    Bhi[idx] = hv;
    Blo[idx] = (f16)(x - (float)hv);
  }
}

// ============================ launcher ======================================
extern "C" void kernel_launch(void* const* d_in, const int* in_sizes, int n_in,
                              void* d_out, int out_size, void* d_ws, size_t ws_size,
                              hipStream_t stream) {
  const float* input    = (const float*)d_in[0];
  const float* Wq       = (const float*)d_in[1];
  const float* Wk       = (const float*)d_in[2];
  const float* Wv       = (const float*)d_in[3];
  const float* Wo       = (const float*)d_in[4];
  const float* Wr       = (const float*)d_in[5];
  const float* br       = (const float*)d_in[6];
  const float* R        = (const float*)d_in[7];
  const float* rel_bias = (const float*)d_in[8];

  float* ws = (float*)d_ws;
  const size_t SEG = 4194304;               // 4M floats = 16MB
  float* q_ws  = ws;                        // q f32 -> role_scores f32
  float* k_ws  = ws + SEG;                  // k f32 -> bound hi/lo
  float* v_ws  = ws + 2 * SEG;              // v f32 -> WT(Wr/Wo) hi/lo
  float* seg3  = ws + 3 * SEG;              // WT(Wq/Wk/Wv) -> vbar hi/lo
  float* rm_ws = ws + 4 * SEG;              // 4096 floats
  float* tab_ws = rm_ws + 4096;             // 2047*16 floats

  f16* in_hi = (f16*)d_out;                 // d_out as scratch (16MB), dead
  f16* in_lo = in_hi + SEG;                 //   before final gemm writes out
  f16* wt_hi = (f16*)seg3;                  // 1M f16 each (4MB total)
  f16* wt_lo = wt_hi + 1048576;
  f16* vb_hi = (f16*)seg3;                  // after QKV gemms: whole seg3
  f16* vb_lo = vb_hi + SEG;
  f16* wt2_hi = (f16*)v_ws;                 // after attn: v dead
  f16* wt2_lo = wt2_hi + 1048576;
  f16* bd_hi = (f16*)k_ws;                  // after attn: k dead
  f16* bd_lo = bd_hi + SEG;

  build_bias_tab<<<128, 256, 0, stream>>>(rel_bias, tab_ws);
  normalize_R<<<64, 64, 0, stream>>>(R, rm_ws);
  split_rows<<<2048, 256, 0, stream>>>(input, in_hi, in_lo);

  dim3 gg(DMODEL / GBN, NROWS / GBM);       // (16, 32)
  transpose_split<<<256, 256, 0, stream>>>(Wq, wt_hi, wt_lo);
  gemm16<1><<<gg, 256, 0, stream>>>(in_hi, in_lo, wt_hi, wt_lo, nullptr, q_ws);
  transpose_split<<<256, 256, 0, stream>>>(Wk, wt_hi, wt_lo);
  gemm16<1><<<gg, 256, 0, stream>>>(in_hi, in_lo, wt_hi, wt_lo, nullptr, k_ws);
  transpose_split<<<256, 256, 0, stream>>>(Wv, wt_hi, wt_lo);
  gemm16<1><<<gg, 256, 0, stream>>>(in_hi, in_lo, wt_hi, wt_lo, nullptr, v_ws);

  attn_f32<<<dim3(QLEN / BQ, BS * N_HEADS), 256, 0, stream>>>(
      q_ws, k_ws, v_ws, tab_ws, vb_hi, vb_lo);

  transpose_split<<<256, 256, 0, stream>>>(Wr, wt2_hi, wt2_lo);
  gemm16<2><<<gg, 256, 0, stream>>>(vb_hi, vb_lo, wt2_hi, wt2_lo, br, q_ws);
  role_bind<<<4096, 256, 0, stream>>>(q_ws, rm_ws, vb_hi, vb_lo, bd_hi, bd_lo);
  transpose_split<<<256, 256, 0, stream>>>(Wo, wt2_hi, wt2_lo);
  gemm16<0><<<gg, 256, 0, stream>>>(bd_hi, bd_lo, wt2_hi, wt2_lo, nullptr, (float*)d_out);
}

// Round 10
// 517.213 us; speedup vs baseline: 3.2366x; 2.0841x over previous
//
#include <hip/hip_runtime.h>

// ---------------------------------------------------------------------------
// TPAttention: fp16x3-split MFMA GEMMs + fp16 MFMA flash attention.
//  1) build_bias_tab (head-major [16][2047]), normalize_R, split_rows
//  2) gemm16<1>: q,k = input@W -> hi/lo f16 [b,h,s,d]
//     gemm16<3>: v = input@Wv  -> hi f16 TRANSPOSED [b,h,d,s]
//  3) attn_mfma: flash attention, QK^T 3-term hi/lo, PV 2-term (P hi/lo x Vh),
//     P redistributed via XOR-swizzled per-wave LDS; vbar -> hi/lo unshaped
//  4) gemm16<2> role_scores, role_bind, gemm16<0> out
// Workspace ~59 MB (proven bound 64.1 MB).
// ---------------------------------------------------------------------------

typedef _Float16 f16;
typedef _Float16 f16x8 __attribute__((ext_vector_type(8)));
typedef _Float16 f16x4 __attribute__((ext_vector_type(4)));
typedef float f32x4 __attribute__((ext_vector_type(4)));

#define N_HEADS 16
#define D_KV 64
#define QLEN 1024
#define BS 4
#define DMODEL 1024
#define NROWS (BS * QLEN)   // 4096
#define KDIM 1024

__device__ __forceinline__ void ldsload16(const void* g, void* l) {
  __builtin_amdgcn_global_load_lds(
      (const __attribute__((address_space(1))) void*)g,
      (__attribute__((address_space(3))) void*)l, 16, 0, 0);
}

// ============================ bias table ====================================
// tab2[h][rel+1023], h-major so per-head rows are contiguous (L1/L2 friendly)
__global__ void build_bias_tab(const float* __restrict__ rel_bias,
                               float* __restrict__ tab) {
  int idx = blockIdx.x * 256 + threadIdx.x;   // [0, 16*2047)
  if (idx >= 16 * 2047) return;
  int h = idx / 2047;
  int rel = idx % 2047 - 1023;                // rel = k - q
  int n = -rel;
  int ret = 0;
  if (n < 0) { ret = 16; n = -n; }
  int b;
  if (n < 8) {
    b = n;
  } else {
    int e  = 31 - __builtin_clz((unsigned)n);
    int f2 = 2 * e + ((n * n >= (1 << (2 * e + 1))) ? 1 : 0);
    int val = f2 - 6 + 8;
    b = val > 15 ? 15 : val;
  }
  b += ret;
  tab[idx] = rel_bias[b * 16 + h];
}

// ============================ R normalization ===============================
__global__ void normalize_R(const float* __restrict__ R, float* __restrict__ RM) {
  int r = blockIdx.x;
  int d = threadIdx.x;
  float v = R[r * 64 + d];
  float ss = v * v;
  #pragma unroll
  for (int o = 32; o; o >>= 1) ss += __shfl_xor(ss, o);
  RM[r * 64 + d] = v / sqrtf(ss);
}

// ============================ fp32 -> hi/lo fp16 split ======================
__global__ __launch_bounds__(256) void split_rows(
    const float* __restrict__ X, f16* __restrict__ Hi, f16* __restrict__ Lo) {
  size_t i = ((size_t)blockIdx.x * 256 + threadIdx.x) * 8;
  float4 v0 = *(const float4*)(X + i);
  float4 v1 = *(const float4*)(X + i + 4);
  float xs[8] = {v0.x, v0.y, v0.z, v0.w, v1.x, v1.y, v1.z, v1.w};
  f16x8 h8, l8;
  #pragma unroll
  for (int j = 0; j < 8; ++j) {
    f16 h = (f16)xs[j];
    h8[j] = h;
    l8[j] = (f16)(xs[j] - (float)h);
  }
  *(f16x8*)(Hi + i) = h8;
  *(f16x8*)(Lo + i) = l8;
}

// ============== W[K][N] f32 -> WT hi/lo fp16 [N][K] (64x64 tiles) ===========
__global__ __launch_bounds__(256) void transpose_split(
    const float* __restrict__ W, f16* __restrict__ Thi, f16* __restrict__ Tlo) {
  __shared__ float tile[64][65];
  int tid = threadIdx.x;
  int n0 = (blockIdx.x & 15) * 64, k0 = (blockIdx.x >> 4) * 64;
  #pragma unroll
  for (int it = 0; it < 16; ++it) {
    int idx = it * 256 + tid;
    int r = idx >> 6, c = idx & 63;
    tile[r][c] = W[(size_t)(k0 + r) * DMODEL + n0 + c];
  }
  __syncthreads();
  #pragma unroll
  for (int it = 0; it < 16; ++it) {
    int idx = it * 256 + tid;
    int rr = idx >> 6, cc = idx & 63;
    float x = tile[cc][rr];
    f16 hv = (f16)x;
    size_t o = (size_t)(n0 + rr) * KDIM + k0 + cc;
    Thi[o] = hv;
    Tlo[o] = (f16)(x - (float)hv);
  }
}

// ============================ fp16x3 MFMA GEMM ==============================
// EPI 0: f32 [M][1024].  EPI 2: f32 + bias.
// EPI 1: hi/lo f16 scatter to [b,h,s,d].
// EPI 3: hi f16 scatter TRANSPOSED to [b,h,d,s] (packed 4-wide in s).
#define GBM 128
#define GBN 64
#define GBK 32
template<int EPI>
__global__ __launch_bounds__(256) void gemm16(
    const f16* __restrict__ Ahi, const f16* __restrict__ Alo,
    const f16* __restrict__ Bhi, const f16* __restrict__ Blo,
    const float* __restrict__ bias, float* __restrict__ C,
    f16* __restrict__ Ch, f16* __restrict__ Cl) {
  __shared__ __align__(16) char smem[24 * 1024];
  char* AHI = smem;
  char* ALO = smem + 8192;
  char* BHI = smem + 16384;
  char* BLO = smem + 20480;

  const int tid = threadIdx.x;
  const int lane = tid & 63, wid = tid >> 6;
  const int wr = wid >> 1, wc = wid & 1;
  const int row0 = blockIdx.y * GBM, col0 = blockIdx.x * GBN;
  const int lr = lane & 15, lk = (lane >> 4) << 3;

  const size_t aoff0 = (size_t)(row0 + wid * 16 + lr) * KDIM + lk;
  const size_t aoff1 = (size_t)(row0 + (wid + 4) * 16 + lr) * KDIM + lk;
  const size_t boff  = (size_t)(col0 + wid * 16 + lr) * KDIM + lk;

  f32x4 acc[4][2] = {};

  for (int k0 = 0; k0 < KDIM; k0 += GBK) {
    ldsload16(Ahi + aoff0 + k0, AHI + wid * 1024);
    ldsload16(Ahi + aoff1 + k0, AHI + (wid + 4) * 1024);
    ldsload16(Alo + aoff0 + k0, ALO + wid * 1024);
    ldsload16(Alo + aoff1 + k0, ALO + (wid + 4) * 1024);
    ldsload16(Bhi + boff + k0, BHI + wid * 1024);
    ldsload16(Blo + boff + k0, BLO + wid * 1024);
    __syncthreads();

    f16x8 ah[4], al[4], bh[2], bl[2];
    #pragma unroll
    for (int mi = 0; mi < 4; ++mi) {
      ah[mi] = *(const f16x8*)(AHI + (wr * 4 + mi) * 1024 + lane * 16);
      al[mi] = *(const f16x8*)(ALO + (wr * 4 + mi) * 1024 + lane * 16);
    }
    #pragma unroll
    for (int ni = 0; ni < 2; ++ni) {
      bh[ni] = *(const f16x8*)(BHI + (wc * 2 + ni) * 1024 + lane * 16);
      bl[ni] = *(const f16x8*)(BLO + (wc * 2 + ni) * 1024 + lane * 16);
    }
    #pragma unroll
    for (int mi = 0; mi < 4; ++mi)
      #pragma unroll
      for (int ni = 0; ni < 2; ++ni) {
        acc[mi][ni] = __builtin_amdgcn_mfma_f32_16x16x32_f16(ah[mi], bh[ni], acc[mi][ni], 0, 0, 0);
        acc[mi][ni] = __builtin_amdgcn_mfma_f32_16x16x32_f16(al[mi], bh[ni], acc[mi][ni], 0, 0, 0);
        acc[mi][ni] = __builtin_amdgcn_mfma_f32_16x16x32_f16(ah[mi], bl[ni], acc[mi][ni], 0, 0, 0);
      }
    __syncthreads();
  }

  #pragma unroll
  for (int mi = 0; mi < 4; ++mi) {
    #pragma unroll
    for (int ni = 0; ni < 2; ++ni) {
      int c = col0 + wc * 32 + ni * 16 + lr;
      int rbase = row0 + wr * 64 + mi * 16 + (lane >> 4) * 4;
      if (EPI == 3) {
        // transposed hi-only: [b,h,d,s], 4 consecutive s packed
        int b_ = rbase >> 10, s0 = rbase & 1023, h = c >> 6, d = c & 63;
        f16x4 hv;
        #pragma unroll
        for (int r = 0; r < 4; ++r) hv[r] = (f16)acc[mi][ni][r];
        *(f16x4*)(Ch + ((size_t)(b_ * 16 + h) << 16) + d * 1024 + s0) = hv;
      } else {
        #pragma unroll
        for (int r = 0; r < 4; ++r) {
          int rr = rbase + r;
          float v = acc[mi][ni][r];
          if (EPI == 2) v += bias[c];
          if (EPI == 1) {
            int b_ = rr >> 10, s = rr & 1023, h = c >> 6, d = c & 63;
            size_t o = ((size_t)(b_ * 16 + h) << 16) + (s << 6) + d;
            f16 hv = (f16)v;
            Ch[o] = hv;
            Cl[o] = (f16)(v - (float)hv);
          } else {
            C[(size_t)rr * DMODEL + c] = v;
          }
        }
      }
    }
  }
}

// ============================ MFMA flash attention ==========================
// grid (QLEN/64, BS*N_HEADS), block 256 (4 waves x 16 q-rows).
// Qh/Ql/Kh/Kl: f16 [b,h,s,d]; Vt: f16 [b,h,d,s].
// S = QK^T 3-term hi/lo; bias from tab2[h][rel+1023]; online softmax;
// P hi/lo -> XOR-swizzled per-wave LDS -> A-frags; PV 2-term vs V-hi.
// Writes vbar hi/lo f16 unshaped [(b*1024+q)*1024 + h*64 + d].
__global__ __launch_bounds__(256) void attn_mfma(
    const f16* __restrict__ Qh, const f16* __restrict__ Ql,
    const f16* __restrict__ Kh, const f16* __restrict__ Kl,
    const f16* __restrict__ Vt, const float* __restrict__ tab2,
    f16* __restrict__ vb_hi, f16* __restrict__ vb_lo) {
  __shared__ __align__(16) char sm[40 * 1024];
  char* KH = sm;              // 8KB: (ni*2+kb)*1024, frag-major
  char* KL = sm + 8192;       // 8KB
  char* VH = sm + 16384;      // 8KB: (nd*2+kb)*1024
  char* PH = sm + 24576;      // 8KB: per-wave 2KB, [q][k] swizzled
  char* PL = sm + 32768;      // 8KB

  const int tid = threadIdx.x;
  const int l = tid & 63, w = tid >> 6;
  const int lr = l & 15, lg = l >> 4;
  const int bh = blockIdx.y, h = bh & 15;
  const int q0 = blockIdx.x * 64;
  const size_t base = (size_t)bh << 16;

  // Q fragments (registers, reused all k-tiles)
  const size_t qrow = base + (size_t)(q0 + w * 16 + lr) * 64 + lg * 8;
  f16x8 qh[2], ql[2];
  qh[0] = *(const f16x8*)(Qh + qrow);
  qh[1] = *(const f16x8*)(Qh + qrow + 32);
  ql[0] = *(const f16x8*)(Ql + qrow);
  ql[1] = *(const f16x8*)(Ql + qrow + 32);

  float m_run[4] = {-1e30f, -1e30f, -1e30f, -1e30f};
  float l_run[4] = {};
  f32x4 o4[4] = {};
  // bias: tab2[h*2047 + 1023 + k - q]
  const int bconst = h * 2047 + 1023 - (q0 + w * 16 + lg * 4);

  for (int k0 = 0; k0 < QLEN; k0 += 64) {
    // stage K/V tile: wave w stages group w of each array
    {
      const f16* ks = Kh + base + (size_t)(k0 + w * 16 + lr) * 64 + lg * 8;
      ldsload16(ks,      KH + (w * 2 + 0) * 1024);
      ldsload16(ks + 32, KH + (w * 2 + 1) * 1024);
      const f16* ks2 = Kl + base + (size_t)(k0 + w * 16 + lr) * 64 + lg * 8;
      ldsload16(ks2,      KL + (w * 2 + 0) * 1024);
      ldsload16(ks2 + 32, KL + (w * 2 + 1) * 1024);
      const f16* vs = Vt + base + (size_t)(w * 16 + lr) * 1024 + k0 + lg * 8;
      ldsload16(vs,      VH + (w * 2 + 0) * 1024);
      ldsload16(vs + 32, VH + (w * 2 + 1) * 1024);
    }
    __syncthreads();

    // S fragments: col k = k0+ni*16+lr, rows q = q0+w*16+lg*4+r
    f32x4 s4[4];
    #pragma unroll
    for (int ni = 0; ni < 4; ++ni) {
      f16x8 kh0 = *(const f16x8*)(KH + (ni * 2 + 0) * 1024 + l * 16);
      f16x8 kh1 = *(const f16x8*)(KH + (ni * 2 + 1) * 1024 + l * 16);
      f16x8 kl0 = *(const f16x8*)(KL + (ni * 2 + 0) * 1024 + l * 16);
      f16x8 kl1 = *(const f16x8*)(KL + (ni * 2 + 1) * 1024 + l * 16);
      f32x4 a = {};
      a = __builtin_amdgcn_mfma_f32_16x16x32_f16(qh[0], kh0, a, 0, 0, 0);
      a = __builtin_amdgcn_mfma_f32_16x16x32_f16(qh[1], kh1, a, 0, 0, 0);
      a = __builtin_amdgcn_mfma_f32_16x16x32_f16(ql[0], kh0, a, 0, 0, 0);
      a = __builtin_amdgcn_mfma_f32_16x16x32_f16(ql[1], kh1, a, 0, 0, 0);
      a = __builtin_amdgcn_mfma_f32_16x16x32_f16(qh[0], kl0, a, 0, 0, 0);
      a = __builtin_amdgcn_mfma_f32_16x16x32_f16(qh[1], kl1, a, 0, 0, 0);
      s4[ni] = a;
    }
    // bias add
    #pragma unroll
    for (int ni = 0; ni < 4; ++ni)
      #pragma unroll
      for (int r = 0; r < 4; ++r)
        s4[ni][r] += tab2[bconst + (k0 + ni * 16 + lr) - r];

    // online softmax (row r shared across the 16-lane group)
    float m_new[4], scl[4], rs[4];
    #pragma unroll
    for (int r = 0; r < 4; ++r) {
      float m = fmaxf(fmaxf(s4[0][r], s4[1][r]), fmaxf(s4[2][r], s4[3][r]));
      #pragma unroll
      for (int off = 1; off < 16; off <<= 1) m = fmaxf(m, __shfl_xor(m, off));
      m_new[r] = fmaxf(m_run[r], m);
      scl[r] = __expf(m_run[r] - m_new[r]);
      m_run[r] = m_new[r];
      rs[r] = 0.f;
    }
    // P = exp(S - m), write hi/lo to swizzled LDS
    #pragma unroll
    for (int ni = 0; ni < 4; ++ni) {
      #pragma unroll
      for (int r = 0; r < 4; ++r) {
        float p = __expf(s4[ni][r] - m_new[r]);
        rs[r] += p;
        f16 ph = (f16)p;
        f16 pl = (f16)(p - (float)ph);
        int qq = lg * 4 + r, kk = ni * 16 + lr;
        int off = w * 2048 + qq * 128 + ((kk * 2) ^ ((qq & 7) << 4));
        *(f16*)(PH + off) = ph;
        *(f16*)(PL + off) = pl;
      }
    }
    #pragma unroll
    for (int r = 0; r < 4; ++r) {
      float s = rs[r];
      #pragma unroll
      for (int off = 1; off < 16; off <<= 1) s += __shfl_xor(s, off);
      l_run[r] = l_run[r] * scl[r] + s;
    }
    // rescale O
    #pragma unroll
    for (int nd = 0; nd < 4; ++nd)
      #pragma unroll
      for (int r = 0; r < 4; ++r) o4[nd][r] *= scl[r];

    // PV: A = P (row q=lr, k-slice kb*32+lg*8), B = V-hi
    const int poff0 = w * 2048 + lr * 128 + ((lg * 16) ^ ((lr & 7) << 4));
    const int poff1 = w * 2048 + lr * 128 + ((64 + lg * 16) ^ ((lr & 7) << 4));
    f16x8 pah0 = *(const f16x8*)(PH + poff0);
    f16x8 pah1 = *(const f16x8*)(PH + poff1);
    f16x8 pal0 = *(const f16x8*)(PL + poff0);
    f16x8 pal1 = *(const f16x8*)(PL + poff1);
    #pragma unroll
    for (int nd = 0; nd < 4; ++nd) {
      f16x8 vh0 = *(const f16x8*)(VH + (nd * 2 + 0) * 1024 + l * 16);
      f16x8 vh1 = *(const f16x8*)(VH + (nd * 2 + 1) * 1024 + l * 16);
      o4[nd] = __builtin_amdgcn_mfma_f32_16x16x32_f16(pah0, vh0, o4[nd], 0, 0, 0);
      o4[nd] = __builtin_amdgcn_mfma_f32_16x16x32_f16(pah1, vh1, o4[nd], 0, 0, 0);
      o4[nd] = __builtin_amdgcn_mfma_f32_16x16x32_f16(pal0, vh0, o4[nd], 0, 0, 0);
      o4[nd] = __builtin_amdgcn_mfma_f32_16x16x32_f16(pal1, vh1, o4[nd], 0, 0, 0);
    }
    __syncthreads();
  }

  // epilogue: vbar unshaped hi/lo
  const int b_ = bh >> 4;
  #pragma unroll
  for (int r = 0; r < 4; ++r) {
    float inv = 1.f / l_run[r];
    int q = q0 + w * 16 + lg * 4 + r;
    size_t rowb = ((size_t)(b_ * 1024 + q) << 10) + h * 64;
    #pragma unroll
    for (int nd = 0; nd < 4; ++nd) {
      float x = o4[nd][r] * inv;
      f16 hv = (f16)x;
      vb_hi[rowb + nd * 16 + lr] = hv;
      vb_lo[rowb + nd * 16 + lr] = (f16)(x - (float)hv);
    }
  }
}

// ============================ role binding ==================================
__global__ __launch_bounds__(256) void role_bind(
    const float* __restrict__ role_scores, const float* __restrict__ RM,
    const f16* __restrict__ Vhi, const f16* __restrict__ Vlo,
    f16* __restrict__ Bhi, f16* __restrict__ Blo) {
  __shared__ float rm[64][64];
  int tid = threadIdx.x;
  #pragma unroll
  for (int p = 0; p < 4; ++p) {
    int idx = tid + p * 256;
    ((float4*)rm)[idx] = ((const float4*)RM)[idx];
  }
  __syncthreads();
  int wave = tid >> 6, lane = tid & 63;
  #pragma unroll
  for (int i = 0; i < 4; ++i) {
    int row = blockIdx.x * 16 + wave * 4 + i;
    int bq = row >> 4, h = row & 15;
    float s = role_scores[((size_t)bq << 10) + h * 64 + lane];
    float m = s;
    #pragma unroll
    for (int o = 32; o; o >>= 1) m = fmaxf(m, __shfl_xor(m, o));
    float e = expf(s - m);
    float l = e;
    #pragma unroll
    for (int o = 32; o; o >>= 1) l += __shfl_xor(l, o);
    float a = e / l;
    float rd = 0.f;
    #pragma unroll
    for (int r = 0; r < 64; ++r) rd += __shfl(a, r) * rm[r][lane];
    size_t idx = ((size_t)bq << 10) + h * 64 + lane;
    float vb = (float)Vhi[idx] + (float)Vlo[idx];
    float x = vb * rd;
    f16 hv = (f16)x;
    Bhi[idx] = hv;
    Blo[idx] = (f16)(x - (float)hv);
  }
}

// ============================ launcher ======================================
extern "C" void kernel_launch(void* const* d_in, const int* in_sizes, int n_in,
                              void* d_out, int out_size, void* d_ws, size_t ws_size,
                              hipStream_t stream) {
  const float* input    = (const float*)d_in[0];
  const float* Wq       = (const float*)d_in[1];
  const float* Wk       = (const float*)d_in[2];
  const float* Wv       = (const float*)d_in[3];
  const float* Wo       = (const float*)d_in[4];
  const float* Wr       = (const float*)d_in[5];
  const float* br       = (const float*)d_in[6];
  const float* R        = (const float*)d_in[7];
  const float* rel_bias = (const float*)d_in[8];

  char* W = (char*)d_ws;
  const size_t MB84 = 8388608;   // one f16 [b,h,s,d] buffer
  f16*   Qh    = (f16*)(W);                  // dead after attn -> wt2
  f16*   Qlo   = (f16*)(W + MB84);           // dead after attn -> bd_hi
  f16*   Khh   = (f16*)(W + 2 * MB84);       // dead after attn -> rs (f32, 2 slots)
  f16*   Kll   = (f16*)(W + 3 * MB84);
  f16*   Vtt   = (f16*)(W + 4 * MB84);       // dead after attn -> bd_lo
  f16*   vb_hi = (f16*)(W + 5 * MB84);       // wt/wt3 slot before/after its lifetime
  f16*   vb_lo = (f16*)(W + 6 * MB84);
  float* tab2  = (float*)(W + 7 * MB84);     // 16*2047*4 = 131008 B
  float* rm_ws = (float*)(W + 7 * MB84 + 131072);   // 16 KB

  f16* in_hi = (f16*)d_out;                  // d_out scratch, dead before final gemm
  f16* in_lo = in_hi + 4194304;
  f16* wt_hi = vb_hi;                        // 2MB each, inside vb slot (pre-attn)
  f16* wt_lo = wt_hi + 1048576;
  f16* wt2_hi = Qh;                          // post-attn slots
  f16* wt2_lo = wt2_hi + 1048576;
  float* rs_ws = (float*)(W + 2 * MB84);     // 16MB over Kh+Kl
  f16* bd_hi = Qlo;
  f16* bd_lo = Vtt;
  f16* wt3_hi = vb_hi;                       // after role_bind, vb dead
  f16* wt3_lo = wt3_hi + 1048576;

  build_bias_tab<<<128, 256, 0, stream>>>(rel_bias, tab2);
  normalize_R<<<64, 64, 0, stream>>>(R, rm_ws);
  split_rows<<<2048, 256, 0, stream>>>(input, in_hi, in_lo);

  dim3 gg(DMODEL / GBN, NROWS / GBM);        // (16, 32)
  transpose_split<<<256, 256, 0, stream>>>(Wq, wt_hi, wt_lo);
  gemm16<1><<<gg, 256, 0, stream>>>(in_hi, in_lo, wt_hi, wt_lo, nullptr, nullptr, Qh, Qlo);
  transpose_split<<<256, 256, 0, stream>>>(Wk, wt_hi, wt_lo);
  gemm16<1><<<gg, 256, 0, stream>>>(in_hi, in_lo, wt_hi, wt_lo, nullptr, nullptr, Khh, Kll);
  transpose_split<<<256, 256, 0, stream>>>(Wv, wt_hi, wt_lo);
  gemm16<3><<<gg, 256, 0, stream>>>(in_hi, in_lo, wt_hi, wt_lo, nullptr, nullptr, Vtt, nullptr);

  attn_mfma<<<dim3(QLEN / 64, BS * N_HEADS), 256, 0, stream>>>(
      Qh, Qlo, Khh, Kll, Vtt, tab2, vb_hi, vb_lo);

  transpose_split<<<256, 256, 0, stream>>>(Wr, wt2_hi, wt2_lo);
  gemm16<2><<<gg, 256, 0, stream>>>(vb_hi, vb_lo, wt2_hi, wt2_lo, br, rs_ws, nullptr, nullptr);
  role_bind<<<4096, 256, 0, stream>>>(rs_ws, rm_ws, vb_hi, vb_lo, bd_hi, bd_lo);
  transpose_split<<<256, 256, 0, stream>>>(Wo, wt3_hi, wt3_lo);
  gemm16<0><<<gg, 256, 0, stream>>>(bd_hi, bd_lo, wt3_hi, wt3_lo, nullptr, (float*)d_out, nullptr, nullptr);
}